// Round 7
// baseline (312.734 us; speedup 1.0000x reference)
//
#include <hip/hip_runtime.h>

static constexpr int B_    = 64;
static constexpr int N_    = 2048;
static constexpr int DI_   = 8;
static constexpr int O_    = 32;
static constexpr int P_    = 16;
static constexpr int OP_   = O_ * P_;      // 512
static constexpr int M_    = OP_ * B_;     // 32768 s elements
static constexpr int CHUNK_ = 4;
static constexpr int NBLK_  = N_ / CHUNK_; // 512

// MODE 0: iter0 (uniform rw; 1/32 folded into v_kernel). No softmax, no v.
// MODE 1: merged A+B per nn; u=exp(a)*preds in regs; Z via 16 LDS pair-sums.
// MODE 2: MODE1 + normalized rw to rw_out (v_in = v0+v1 by linearity);
//         exps stored individually, rw row written by wave==nn (contiguous 128B).
// Register hygiene: no address-of on privates; all private-array loops fully
// unrolled with constant indices (alloca->scratch was the R1/R4/R5 killer).
template <int MODE, bool ATOMIC>
__global__ __launch_bounds__(1024, 4)
void fused_pass(const float* __restrict__ x, const float* __restrict__ W,
                const float* __restrict__ v_in, float* __restrict__ s_out,
                float* __restrict__ rw_out) {
  __shared__ float x_lds[CHUNK_ * 8 * 65];   // [rem=(nn*8+i)][b], pad 65 (8.3 KB)
  __shared__ float a_lds[2][O_ * B_];        // double-buffered exp storage (16 KB)
  const int tid  = threadIdx.x;
  const int lane = tid & 63;                 // lane == batch b
  const int wave = tid >> 6;                 // 0..15; wave owns o = 2w, 2w+1
  const int n0   = blockIdx.x * CHUNK_;

  // stage x[b][n0..n0+3][i] -> LDS (coalesced; conflict-free writes)
  #pragma unroll
  for (int k = 0; k < 2; ++k) {
    int d = k * 1024 + tid;
    int b = d >> 5, rem = d & 31;
    x_lds[rem * 65 + b] = x[b * (N_ * DI_) + n0 * DI_ + rem];
  }

  float s_r[32];
  #pragma unroll
  for (int q = 0; q < 32; ++q) s_r[q] = 0.0f;

  __syncthreads();

  #pragma unroll 1
  for (int nn = 0; nn < CHUNK_; ++nn) {
    const int n = n0 + nn;
    float xr[8];
    #pragma unroll
    for (int i = 0; i < 8; ++i) xr[i] = x_lds[(nn * 8 + i) * 65 + lane];

    float u[2][16];   // preds, then e*preds (in place)
    float e0 = 0.0f, e1 = 0.0f;

    #pragma unroll
    for (int oo = 0; oo < 2; ++oo) {
      const int o_u = __builtin_amdgcn_readfirstlane(wave * 2 + oo);
      const float* wp = W + (size_t)(n * O_ + o_u) * (P_ * DI_);

      float4 va0, va1, va2, va3;
      if (MODE != 0) {
        const float4* vp =
            (const float4*)(v_in + (size_t)lane * OP_ + (wave * 2 + oo) * P_);
        va0 = vp[0]; va1 = vp[1]; va2 = vp[2]; va3 = vp[3];
      }

      float acc = 0.0f;
      #pragma unroll
      for (int p = 0; p < P_; ++p) {
        float pv = wp[p * 8 + 0] * xr[0];
        pv = __builtin_fmaf(wp[p * 8 + 1], xr[1], pv);
        pv = __builtin_fmaf(wp[p * 8 + 2], xr[2], pv);
        pv = __builtin_fmaf(wp[p * 8 + 3], xr[3], pv);
        pv = __builtin_fmaf(wp[p * 8 + 4], xr[4], pv);
        pv = __builtin_fmaf(wp[p * 8 + 5], xr[5], pv);
        pv = __builtin_fmaf(wp[p * 8 + 6], xr[6], pv);
        pv = __builtin_fmaf(wp[p * 8 + 7], xr[7], pv);
        if (MODE == 0) {
          s_r[oo * 16 + p] += pv;
        } else {
          u[oo][p] = pv;
          const float vc = (p < 4)  ? ((p & 3) == 0 ? va0.x : (p & 3) == 1 ? va0.y : (p & 3) == 2 ? va0.z : va0.w)
                         : (p < 8)  ? ((p & 3) == 0 ? va1.x : (p & 3) == 1 ? va1.y : (p & 3) == 2 ? va1.z : va1.w)
                         : (p < 12) ? ((p & 3) == 0 ? va2.x : (p & 3) == 1 ? va2.y : (p & 3) == 2 ? va2.z : va2.w)
                                    : ((p & 3) == 0 ? va3.x : (p & 3) == 1 ? va3.y : (p & 3) == 2 ? va3.z : va3.w);
          acc = __builtin_fmaf(pv, vc, acc);
        }
      }
      if (MODE != 0) {
        // no-max softmax: |logit| <= ~3 analytically (|v|<=1 or 2, |preds|~1)
        const float e = __expf(acc);
        if (oo == 0) e0 = e; else e1 = e;
        #pragma unroll
        for (int p = 0; p < P_; ++p) u[oo][p] *= e;   // u = e * preds
      }
    }

    if (MODE != 0) {
      const int buf = nn & 1;
      if (MODE == 1) {
        a_lds[buf][wave * B_ + lane] = e0 + e1;       // pair partial
      } else {
        a_lds[buf][(wave * 2 + 0) * B_ + lane] = e0;  // individual exps
        a_lds[buf][(wave * 2 + 1) * B_ + lane] = e1;
      }
      __syncthreads();

      float Z = 0.0f;
      if (MODE == 1) {
        #pragma unroll
        for (int w = 0; w < 16; ++w) Z += a_lds[buf][w * B_ + lane];
      } else {
        #pragma unroll
        for (int o = 0; o < O_; ++o) Z += a_lds[buf][o * B_ + lane];
      }
      const float rZ = __builtin_amdgcn_rcpf(Z);

      #pragma unroll
      for (int p = 0; p < P_; ++p) {
        s_r[p]      = __builtin_fmaf(rZ, u[0][p], s_r[p]);
        s_r[16 + p] = __builtin_fmaf(rZ, u[1][p], s_r[16 + p]);
      }

      if (MODE == 2 && wave == nn) {
        float* rp = rw_out + ((size_t)lane * N_ + n) * O_;
        #pragma unroll
        for (int o4 = 0; o4 < 8; ++o4) {
          float4 t;
          t.x = a_lds[buf][(o4 * 4 + 0) * B_ + lane] * rZ;
          t.y = a_lds[buf][(o4 * 4 + 1) * B_ + lane] * rZ;
          t.z = a_lds[buf][(o4 * 4 + 2) * B_ + lane] * rZ;
          t.w = a_lds[buf][(o4 * 4 + 3) * B_ + lane] * rZ;
          ((float4*)rp)[o4] = t;
        }
      }
    }
  }

  // epilogue: block partial (layout [blk][q=o*16+p][b]) or atomic fallback
  if (ATOMIC) {
    #pragma unroll
    for (int oo = 0; oo < 2; ++oo) {
      float* sp = s_out + (size_t)((wave * 2 + oo) * P_) * B_ + lane;
      #pragma unroll
      for (int p = 0; p < P_; ++p) atomicAdd(&sp[p * B_], s_r[oo * 16 + p]);
    }
  } else {
    #pragma unroll
    for (int oo = 0; oo < 2; ++oo) {
      float* sp = s_out + (size_t)blockIdx.x * M_ +
                  (size_t)((wave * 2 + oo) * P_) * B_ + lane;
      #pragma unroll
      for (int p = 0; p < P_; ++p) sp[p * B_] = s_r[oo * 16 + p];
    }
  }
}

// stage-1 reduction: P[K][M_] -> P2[16][M_]; grid 16 groups x 16 m-chunks.
__global__ __launch_bounds__(1024)
void reduce1(const float* __restrict__ spart, float* __restrict__ p2, int K) {
  const int g  = blockIdx.x >> 4;
  const int mc = blockIdx.x & 15;
  const int kpg = K >> 4;
  const int m0 = mc * 2048 + threadIdx.x;
  float a0 = 0.0f, a1 = 0.0f;
  const float* p = spart + (size_t)(g * kpg) * M_;
  for (int k = 0; k < kpg; ++k) {
    a0 += p[(size_t)k * M_ + m0];
    a1 += p[(size_t)k * M_ + m0 + 1024];
  }
  p2[(size_t)g * M_ + m0]        = a0;
  p2[(size_t)g * M_ + m0 + 1024] = a1;
}

// sum ngroups (stride M_) + squash; optionally add v_add; optionally zero a buffer.
__global__ __launch_bounds__(1024)
void v_kernel(const float* __restrict__ src, int ngroups, float scale,
              const float* __restrict__ v_add, float* __restrict__ v_out,
              float* __restrict__ zero_buf) {
  __shared__ float sq[P_ * 64];
  const int t = threadIdx.x;
  const int b = t & 63;
  const int p = t >> 6;
  const int o = blockIdx.x;
  const int q = o * P_ + p;
  float acc = 0.0f;
  for (int g = 0; g < ngroups; ++g) acc += src[(size_t)g * M_ + q * 64 + b];
  acc *= scale;
  sq[p * 64 + b] = acc * acc;
  if (zero_buf) zero_buf[blockIdx.x * 1024 + t] = 0.0f;
  __syncthreads();
  float s2 = 0.0f;
  #pragma unroll
  for (int pp = 0; pp < P_; ++pp) s2 += sq[pp * 64 + b];
  float sc = (s2 / (1.0f + s2)) / sqrtf(s2 + 1e-7f);
  float v = acc * sc;
  const int idx = b * OP_ + q;   // v layout [b][o][p]
  v_out[idx] = v + (v_add ? v_add[idx] : 0.0f);
}

extern "C" void kernel_launch(void* const* d_in, const int* in_sizes, int n_in,
                              void* d_out, int out_size, void* d_ws, size_t ws_size,
                              hipStream_t stream) {
  (void)in_sizes; (void)n_in; (void)out_size;
  const float* x = (const float*)d_in[0];
  const float* W = (const float*)d_in[1];
  float* out_v  = (float*)d_out;                       // [64][32][16]
  float* out_rw = out_v + (size_t)B_ * O_ * P_;        // [64][2048][32]
  float* vws   = (float*)d_ws;                         // v0
  float* vsum  = vws + M_;                             // v0+v1
  float* p2    = vsum + M_;                            // 16 * M_
  float* spart = p2 + 16 * M_;                         // NBLK_ * M_

  const size_t need = (size_t)(2 * M_ + 16 * M_ + (size_t)NBLK_ * M_) * 4;

  dim3 gF(NBLK_), bF(1024), gV(O_), bV(1024), gR(256);
  if (ws_size >= need) {
    fused_pass<0, false><<<gF, bF, 0, stream>>>(x, W, nullptr, spart, nullptr);
    reduce1<<<gR, bF, 0, stream>>>(spart, p2, NBLK_);
    v_kernel<<<gV, bV, 0, stream>>>(p2, 16, 1.0f / 32.0f, nullptr, vws, nullptr);
    fused_pass<1, false><<<gF, bF, 0, stream>>>(x, W, vws, spart, nullptr);
    reduce1<<<gR, bF, 0, stream>>>(spart, p2, NBLK_);
    v_kernel<<<gV, bV, 0, stream>>>(p2, 16, 1.0f, vws, vsum, nullptr);
    fused_pass<2, false><<<gF, bF, 0, stream>>>(x, W, vsum, spart, out_rw);
    reduce1<<<gR, bF, 0, stream>>>(spart, p2, NBLK_);
    v_kernel<<<gV, bV, 0, stream>>>(p2, 16, 1.0f, nullptr, out_v, nullptr);
  } else {
    // atomic fallback for small ws
    float* sAb = p2;
    float* sBb = sAb + M_;
    hipMemsetAsync(sAb, 0, (size_t)M_ * sizeof(float), stream);
    fused_pass<0, true><<<gF, bF, 0, stream>>>(x, W, nullptr, sAb, nullptr);
    v_kernel<<<gV, bV, 0, stream>>>(sAb, 1, 1.0f / 32.0f, nullptr, vws, sBb);
    fused_pass<1, true><<<gF, bF, 0, stream>>>(x, W, vws, sBb, nullptr);
    v_kernel<<<gV, bV, 0, stream>>>(sBb, 1, 1.0f, vws, vsum, sAb);
    fused_pass<2, true><<<gF, bF, 0, stream>>>(x, W, vsum, sAb, out_rw);
    v_kernel<<<gV, bV, 0, stream>>>(sAb, 1, 1.0f, nullptr, out_v, nullptr);
  }
}